// Round 4
// baseline (7045.998 us; speedup 1.0000x reference)
//
#include <hip/hip_runtime.h>
#include <math.h>

// B=512, D_MODEL=1024, D_INNER=2048, DT_RANK=64, D_STATE=64, NBC=192,
// C_OUT=64, PRED_LEN=96.
// R4: fabric-atomic-bound fix. 64 groups (8 batch rows) x 4 slices (512 cols)
// = 256 blocks x 512 threads, 1 block/CU. Fan-in 4 (was 32): atomic ops/step
// drop ~8x. Thread = column; 8 rows in registers; LDS reads are wave-uniform
// broadcasts. Group barrier = 4-block clique via atomic counters.

#define AGENT __HIP_MEMORY_SCOPE_AGENT
typedef unsigned long long ull;
union F2 { ull u; float f[2]; };

__device__ __forceinline__ float sigf(float v){
  return __builtin_amdgcn_rcpf(1.f + __expf(-v));
}

// ---------------- setup kernels ----------------

__global__ __launch_bounds__(256) void k_ctx(
    const float* __restrict__ ctxin, const float* __restrict__ w_in,
    const float* __restrict__ b_in, float* __restrict__ ctx_xz){
  int tid = threadIdx.x;
  int j = blockIdx.x*256 + tid;
  int b0 = blockIdx.y*16;
  const float* cp = ctxin + (size_t)b0*1024;
  float acc[16];
#pragma unroll
  for (int r=0;r<16;r++) acc[r]=0.f;
  for (int k=0;k<1024;k+=4){
    float w0 = w_in[(size_t)(k+0)*4096 + j];
    float w1 = w_in[(size_t)(k+1)*4096 + j];
    float w2 = w_in[(size_t)(k+2)*4096 + j];
    float w3 = w_in[(size_t)(k+3)*4096 + j];
#pragma unroll
    for (int r=0;r<16;r++){
      acc[r] += cp[r*1024+k]*w0 + cp[r*1024+k+1]*w1
              + cp[r*1024+k+2]*w2 + cp[r*1024+k+3]*w3;
    }
  }
  float bj = b_in[j];
#pragma unroll
  for (int r=0;r<16;r++) ctx_xz[(size_t)(b0+r)*4096 + j] = acc[r] + bj;
}

__global__ __launch_bounds__(256) void k_wop(
    const float* __restrict__ w_out, const float* __restrict__ w_proj,
    const float* __restrict__ b_out, const float* __restrict__ b_proj,
    float* __restrict__ W_op, float* __restrict__ b_op){
  int g = blockIdx.x, tid = threadIdx.x;
  if (g == 512){
    if (tid < 64){
      float s = b_proj[tid];
      for (int k=0;k<1024;k++) s += b_out[k]*w_proj[k*64+tid];
      b_op[tid] = s;
    }
    return;
  }
  int idx = g*256 + tid;
  int c = idx>>6, o = idx&63;
  float s = 0.f;
  const float* wr = w_out + (size_t)c*1024;
  for (int k=0;k<1024;k++) s += wr[k]*w_proj[k*64+o];
  W_op[idx] = s;
}

__global__ __launch_bounds__(256) void k_cvec(
    const float* __restrict__ b_op, const float* __restrict__ w_in2,
    float* __restrict__ cvec){
  int j = blockIdx.x*256 + threadIdx.x;
  float s = 0.f;
  for (int o=0;o<64;o++) s += b_op[o]*w_in2[(size_t)o*4096 + j];
  cvec[j] = s;
}

__global__ void k_zero(float* __restrict__ p, int n){
  int i = blockIdx.x*256 + threadIdx.x;
  if (i < n) p[i] = 0.f;
}

// ---------------- persistent step kernel ----------------

__device__ __forceinline__ void gbar(int* flag, int target){
  __syncthreads();             // drains vmcnt(0): all this block's atomics acked
  if (threadIdx.x == 0){
    __hip_atomic_fetch_add(flag, 1, __ATOMIC_RELEASE, AGENT);
    while (__hip_atomic_load(flag, __ATOMIC_RELAXED, AGENT) < target)
      __builtin_amdgcn_s_sleep(1);
  }
  __syncthreads();
}

__global__ __launch_bounds__(512,2) void k_steps(
    const float* __restrict__ ctx_xz, const float* __restrict__ cvec,
    const float* __restrict__ w_in2,  const float* __restrict__ conv_w,
    const float* __restrict__ conv_b, const float* __restrict__ w_x,
    const float* __restrict__ w_dt,   const float* __restrict__ b_dt,
    const float* __restrict__ D_skip, const float* __restrict__ W_op,
    const float* __restrict__ b_op,   const float* __restrict__ initial,
    float* __restrict__ xd0, float* __restrict__ xd1,
    float* __restrict__ pa0, float* __restrict__ pa1,
    int* __restrict__ flags, float* __restrict__ dout)
{
  const int tid  = threadIdx.x;
  const int g    = blockIdx.x & 63;   // group: 8 batch rows; 4 blocks/group on one XCD
  const int s    = blockIdx.x >> 6;   // slice: 512 cols
  const int lane = tid & 63;
  const int r0   = g*8;
  const int k0   = s*512;
  const int jx   = k0 + tid;          // this thread's column (0..2047)
  const int jz   = 2048 + jx;

  __shared__ float predT[64][8];   // phase A: pred [o][row]; phase C: xdbc_dt [o][row]
  __shared__ float xT[512][8];     // phase A: x [col][row]; phase C: redL (8KB of 16)
  __shared__ float yT[512][8];     // [col][row]
  __shared__ float xdBC[8][128];   // B,C segments [row][n]
  __shared__ float bcL[8];
  float* redL = &xT[0][0];

  // step-invariant register preloads
  const float cw  = conv_w[jx*4+3];
  const float cb  = conv_b[jx];
  const float cvx = cvec[jx];
  const float cvz = cvec[jz];
  const float bdt = b_dt[jx];
  const float dsk = D_skip[jx];
  const float bop = b_op[lane];
  float ctxv[8], ctzv[8];
#pragma unroll
  for (int r=0;r<8;r++){
    ctxv[r] = ctx_xz[(size_t)(r0+r)*4096 + jx];
    ctzv[r] = ctx_xz[(size_t)(r0+r)*4096 + jz];
  }
  int* flag = flags + g*32;

  float xv[8], zsv[8];

  for (int t=0; t<96; t++){
    const float* pin = (t&1) ? pa1 : pa0;
    float*       pout= (t&1) ? pa0 : pa1;
    float*       xdc = (t&1) ? xd1 : xd0;
    float*       xdn = (t&1) ? xd0 : xd1;

    // ---- Phase A: stage pred (8B packed), zero pout quarter ----
    if (tid < 256){
      int r = tid >> 5, o2 = (tid & 31)*2;
      F2 v;
      if (t == 0){
        v.f[0] = initial[(size_t)(r0+r)*64 + o2];
        v.f[1] = initial[(size_t)(r0+r)*64 + o2 + 1];
      } else {
        v.u = __hip_atomic_load((const ull*)&pin[(size_t)(r0+r)*64 + o2],
                                __ATOMIC_RELAXED, AGENT);
      }
      predT[o2  ][r] = v.f[0];
      predT[o2+1][r] = v.f[1];
    } else if (tid < 320){
      int i = tid - 256;
      __hip_atomic_store((ull*)&pout[(size_t)g*512 + s*128 + i*2], 0ULL,
                         __ATOMIC_RELAXED, AGENT);
    }
    __syncthreads();
    // dout for step t-1: this block owns rows s*2, s*2+1
    if (t > 0 && tid < 128){
      int r = s*2 + (tid>>6);
      dout[((size_t)(r0+r)*96 + (t-1))*64 + lane] = predT[lane][r] + bop;
    }

    // GEMM1: x and z halves, K=64 over pred
    float acc[8], zac[8];
#pragma unroll
    for (int r=0;r<8;r++){
      acc[r] = ctxv[r] + (t ? cvx : 0.f);
      zac[r] = ctzv[r] + (t ? cvz : 0.f);
    }
#pragma unroll 2
    for (int o=0;o<64;o++){
      float wx = w_in2[(size_t)o*4096 + jx];
      float wz = w_in2[(size_t)o*4096 + jz];
      float4 p0 = *(const float4*)&predT[o][0];
      float4 p1 = *(const float4*)&predT[o][4];
      acc[0]+=p0.x*wx; acc[1]+=p0.y*wx; acc[2]+=p0.z*wx; acc[3]+=p0.w*wx;
      acc[4]+=p1.x*wx; acc[5]+=p1.y*wx; acc[6]+=p1.z*wx; acc[7]+=p1.w*wx;
      zac[0]+=p0.x*wz; zac[1]+=p0.y*wz; zac[2]+=p0.z*wz; zac[3]+=p0.w*wz;
      zac[4]+=p1.x*wz; zac[5]+=p1.y*wz; zac[6]+=p1.z*wz; zac[7]+=p1.w*wz;
    }
#pragma unroll
    for (int r=0;r<8;r++){
      float v = acc[r]*cw + cb;
      xv[r]  = v * sigf(v);
      zsv[r] = zac[r] * sigf(zac[r]);
    }
    *(float4*)&xT[tid][0] = make_float4(xv[0],xv[1],xv[2],xv[3]);
    *(float4*)&xT[tid][4] = make_float4(xv[4],xv[5],xv[6],xv[7]);
    __syncthreads();

    // xdbc partials over this slice's K=512 (384 threads); idle 128 zero xdn
    if (tid < 384){
      int rh = (tid >= 192) ? 1 : 0;
      int n  = tid - rh*192;
      int rb = rh*4;
      float f0=0.f,f1=0.f,f2=0.f,f3=0.f;
#pragma unroll 4
      for (int k=0;k<512;k++){
        float w = w_x[(size_t)(k0+k)*192 + n];
        float4 xk = *(const float4*)&xT[k][rb];
        f0+=xk.x*w; f1+=xk.y*w; f2+=xk.z*w; f3+=xk.w*w;
      }
      atomicAdd(&xdc[(size_t)(r0+rb+0)*192 + n], f0);
      atomicAdd(&xdc[(size_t)(r0+rb+1)*192 + n], f1);
      atomicAdd(&xdc[(size_t)(r0+rb+2)*192 + n], f2);
      atomicAdd(&xdc[(size_t)(r0+rb+3)*192 + n], f3);
    } else {
      int i = tid - 384;   // 0..127: zero this block's quarter of xdn (192 ull)
      ull* base = (ull*)&xdn[(size_t)g*1536];
      __hip_atomic_store(base + s*192 + i, 0ULL, __ATOMIC_RELAXED, AGENT);
      if (i < 64)
        __hip_atomic_store(base + s*192 + 128 + i, 0ULL, __ATOMIC_RELAXED, AGENT);
    }
    gbar(flag, 4*(2*t+1));

    // ---- Phase C ----
    // stage reduced xdbc -> LDS (768 ull total, 8B packed atomic loads)
    {
      int r = tid/96, np = (tid%96)*2;
      F2 v; v.u = __hip_atomic_load((const ull*)&xdc[(size_t)(r0+r)*192 + np],
                                    __ATOMIC_RELAXED, AGENT);
      if (np < 64){ predT[np][r]=v.f[0]; predT[np+1][r]=v.f[1]; }
      else        { xdBC[r][np-64]=v.f[0]; xdBC[r][np-63]=v.f[1]; }
    }
    if (tid < 256){
      int u = 512 + tid;
      int r = u/96, np = (u%96)*2;
      F2 v; v.u = __hip_atomic_load((const ull*)&xdc[(size_t)(r0+r)*192 + np],
                                    __ATOMIC_RELAXED, AGENT);
      if (np < 64){ predT[np][r]=v.f[0]; predT[np+1][r]=v.f[1]; }
      else        { xdBC[r][np-64]=v.f[0]; xdBC[r][np-63]=v.f[1]; }
    }
    __syncthreads();
    // bc dots: wave r handles row r
    {
      int r = tid >> 6;
      float p = xdBC[r][lane]*xdBC[r][64+lane];
#pragma unroll
      for (int sh=1; sh<64; sh<<=1) p += __shfl_xor(p, sh, 64);
      if (lane == 0) bcL[r] = p;
    }
    __syncthreads();

    // dt GEMM (K=64 over xdbc[:, :64]) + y
    float dacc[8];
#pragma unroll
    for (int r=0;r<8;r++) dacc[r]=0.f;
#pragma unroll 2
    for (int o=0;o<64;o++){
      float w = w_dt[(size_t)o*2048 + jx];
      float4 d0 = *(const float4*)&predT[o][0];
      float4 d1 = *(const float4*)&predT[o][4];
      dacc[0]+=d0.x*w; dacc[1]+=d0.y*w; dacc[2]+=d0.z*w; dacc[3]+=d0.w*w;
      dacc[4]+=d1.x*w; dacc[5]+=d1.y*w; dacc[6]+=d1.z*w; dacc[7]+=d1.w*w;
    }
    float yv[8];
#pragma unroll
    for (int r=0;r<8;r++){
      float v = dacc[r] + bdt;
      float dt = (v > 15.f) ? v : __logf(1.f + __expf(v));
      yv[r] = (dt*bcL[r] + dsk) * xv[r] * zsv[r];
    }
    *(float4*)&yT[tid][0] = make_float4(yv[0],yv[1],yv[2],yv[3]);
    *(float4*)&yT[tid][4] = make_float4(yv[4],yv[5],yv[6],yv[7]);
    __syncthreads();

    // pred partials: thread (o, row-half rh, K-quarter kq)
    {
      int o = lane, rh = (tid>>6)&1, kq = tid>>7, rb = rh*4;
      float p0=0.f,p1=0.f,p2=0.f,p3=0.f;
      int kbeg = kq*128;
#pragma unroll 4
      for (int k=kbeg; k<kbeg+128; k++){
        float w = W_op[(size_t)(k0+k)*64 + o];
        float4 y4 = *(const float4*)&yT[k][rb];
        p0+=y4.x*w; p1+=y4.y*w; p2+=y4.z*w; p3+=y4.w*w;
      }
      *(float4*)&redL[tid*4] = make_float4(p0,p1,p2,p3);
    }
    __syncthreads();
    if (tid < 128){
      int o = lane, rh = tid>>6;
      float4 a0 = *(const float4*)&redL[(0*128+tid)*4];
      float4 a1 = *(const float4*)&redL[(1*128+tid)*4];
      float4 a2 = *(const float4*)&redL[(2*128+tid)*4];
      float4 a3 = *(const float4*)&redL[(3*128+tid)*4];
      atomicAdd(&pout[(size_t)(r0+rh*4+0)*64 + o], a0.x+a1.x+a2.x+a3.x);
      atomicAdd(&pout[(size_t)(r0+rh*4+1)*64 + o], a0.y+a1.y+a2.y+a3.y);
      atomicAdd(&pout[(size_t)(r0+rh*4+2)*64 + o], a0.z+a1.z+a2.z+a3.z);
      atomicAdd(&pout[(size_t)(r0+rh*4+3)*64 + o], a0.w+a1.w+a2.w+a3.w);
    }
    gbar(flag, 4*(2*t+2));
  }

  // final pred (t=95 odd -> pa0); this block owns rows s*2, s*2+1
  if (tid < 128){
    int r = s*2 + (tid>>6);
    float v = __hip_atomic_load(&pa0[(size_t)(r0+r)*64 + lane],
                                __ATOMIC_RELAXED, AGENT);
    dout[((size_t)(r0+r)*96 + 95)*64 + lane] = v + bop;
  }
}

// ---------------- launch ----------------

extern "C" void kernel_launch(void* const* d_in, const int* in_sizes, int n_in,
                              void* d_out, int out_size, void* d_ws, size_t ws_size,
                              hipStream_t stream)
{
  const float* context = (const float*)d_in[0];
  const float* initial = (const float*)d_in[1];
  const float* w_in    = (const float*)d_in[2];
  const float* b_in    = (const float*)d_in[3];
  const float* conv_w  = (const float*)d_in[4];
  const float* conv_b  = (const float*)d_in[5];
  const float* w_x     = (const float*)d_in[6];
  const float* w_dt    = (const float*)d_in[7];
  const float* b_dt    = (const float*)d_in[8];
  // d_in[9] = A_log (unused: L=1, h0=0)
  const float* D_skip  = (const float*)d_in[10];
  const float* w_out   = (const float*)d_in[11];
  const float* b_out   = (const float*)d_in[12];
  const float* w_proj  = (const float*)d_in[13];
  const float* b_proj  = (const float*)d_in[14];

  float* ws = (float*)d_ws;
  float* ctx_xz = ws;                    // 2,097,152
  float* cvec   = ctx_xz + 2097152;      // 4,096
  float* W_op   = cvec + 4096;           // 131,072
  float* b_op   = W_op + 131072;         // 128
  float* xd0    = b_op + 128;            // 98,304
  int*   flags  = (int*)(xd0 + 98304);   // 2048 ints (64 groups x 32 stride)
  float* xd1    = xd0 + 98304 + 2048;    // 98,304
  float* pa0    = xd1 + 98304;           // 32,768
  float* pa1    = pa0 + 32768;           // 32,768
  float* dout   = (float*)d_out;

  const float* w_in2 = w_in + (size_t)1024*4096;

  k_wop <<<dim3(513),   256, 0, stream>>>(w_out, w_proj, b_out, b_proj, W_op, b_op);
  k_cvec<<<dim3(16),    256, 0, stream>>>(b_op, w_in2, cvec);
  k_ctx <<<dim3(16,32), 256, 0, stream>>>(context, w_in, b_in, ctx_xz);
  k_zero<<<dim3(393),   256, 0, stream>>>(xd0, 98304 + 2048);  // xd0 + flags

  k_steps<<<dim3(256), 512, 0, stream>>>(ctx_xz, cvec, w_in2, conv_w, conv_b,
                                         w_x, w_dt, b_dt, D_skip, W_op, b_op,
                                         initial, xd0, xd1, pa0, pa1,
                                         flags, dout);
}

// Round 5
// 5665.462 us; speedup vs baseline: 1.2437x; 1.2437x over previous
//
#include <hip/hip_runtime.h>
#include <math.h>

// B=512, D_MODEL=1024, D_INNER=2048, DT_RANK=64, D_STATE=64, NBC=192,
// C_OUT=64, PRED_LEN=96.
// R5: hybrid pair design. 128 groups (4 batch rows) x 2 slices (1024 cols)
// = 256 blocks x 512 threads, 1 block/CU. Blocks g and g+128 pair on the
// same XCD (128 % 8 == 0). Per-CU weight stream 1.75MB/step (L2-resident
// per XCD: 3.5MB total). Cross-block: plain device-scope store/load of
// partials (fan-in 2, no RMW); in-block reduction via LDS ds_add_f32.
// Group barrier = 2-block clique counter.

#define AGENT __HIP_MEMORY_SCOPE_AGENT
typedef unsigned long long ull;
union F2 { ull u; float f[2]; };

__device__ __forceinline__ float sigf(float v){
  return __builtin_amdgcn_rcpf(1.f + __expf(-v));
}

// ---------------- setup kernels ----------------

__global__ __launch_bounds__(256) void k_ctx(
    const float* __restrict__ ctxin, const float* __restrict__ w_in,
    const float* __restrict__ b_in, float* __restrict__ ctx_xz){
  int tid = threadIdx.x;
  int j = blockIdx.x*256 + tid;
  int b0 = blockIdx.y*16;
  const float* cp = ctxin + (size_t)b0*1024;
  float acc[16];
#pragma unroll
  for (int r=0;r<16;r++) acc[r]=0.f;
  for (int k=0;k<1024;k+=4){
    float w0 = w_in[(size_t)(k+0)*4096 + j];
    float w1 = w_in[(size_t)(k+1)*4096 + j];
    float w2 = w_in[(size_t)(k+2)*4096 + j];
    float w3 = w_in[(size_t)(k+3)*4096 + j];
#pragma unroll
    for (int r=0;r<16;r++){
      acc[r] += cp[r*1024+k]*w0 + cp[r*1024+k+1]*w1
              + cp[r*1024+k+2]*w2 + cp[r*1024+k+3]*w3;
    }
  }
  float bj = b_in[j];
#pragma unroll
  for (int r=0;r<16;r++) ctx_xz[(size_t)(b0+r)*4096 + j] = acc[r] + bj;
}

// W_opT[o][c] = sum_k w_out[c][k] * w_proj[k][o]  -> [64][2048]
__global__ __launch_bounds__(256) void k_wop(
    const float* __restrict__ w_out, const float* __restrict__ w_proj,
    const float* __restrict__ b_out, const float* __restrict__ b_proj,
    float* __restrict__ W_opT, float* __restrict__ b_op){
  int g = blockIdx.x, tid = threadIdx.x;
  if (g == 512){
    if (tid < 64){
      float s = b_proj[tid];
      for (int k=0;k<1024;k++) s += b_out[k]*w_proj[k*64+tid];
      b_op[tid] = s;
    }
    return;
  }
  int idx = g*256 + tid;
  int c = idx>>6, o = idx&63;
  float s = 0.f;
  const float* wr = w_out + (size_t)c*1024;
  for (int k=0;k<1024;k++) s += wr[k]*w_proj[k*64+o];
  W_opT[(size_t)o*2048 + c] = s;
}

__global__ __launch_bounds__(256) void k_cvec(
    const float* __restrict__ b_op, const float* __restrict__ w_in2,
    float* __restrict__ cvec){
  int j = blockIdx.x*256 + threadIdx.x;
  float s = 0.f;
  for (int o=0;o<64;o++) s += b_op[o]*w_in2[(size_t)o*4096 + j];
  cvec[j] = s;
}

// w_xT[n][c] = w_x[c][n]   [192][2048]
__global__ __launch_bounds__(256) void k_wxT(
    const float* __restrict__ w_x, float* __restrict__ w_xT){
  int n = threadIdx.x;
  if (n >= 192) return;
  int cb = blockIdx.x*256;
  for (int c=cb; c<cb+256; c++)
    w_xT[(size_t)n*2048 + c] = w_x[(size_t)c*192 + n];
}

__global__ void k_zero(int* __restrict__ p, int n){
  int i = blockIdx.x*256 + threadIdx.x;
  if (i < n) p[i] = 0;
}

// ---------------- persistent step kernel ----------------

__device__ __forceinline__ void gbar(int* flag, int target){
  __syncthreads();             // drains vmcnt: this block's stores are out
  if (threadIdx.x == 0){
    __hip_atomic_fetch_add(flag, 1, __ATOMIC_RELEASE, AGENT);
    while (__hip_atomic_load(flag, __ATOMIC_RELAXED, AGENT) < target)
      __builtin_amdgcn_s_sleep(1);
  }
  __syncthreads();
}

__global__ __launch_bounds__(512,2) void k_steps(
    const float* __restrict__ ctx_xz, const float* __restrict__ cvec,
    const float* __restrict__ w_in2,  const float* __restrict__ conv_w,
    const float* __restrict__ conv_b, const float* __restrict__ w_xT,
    const float* __restrict__ w_dt,   const float* __restrict__ b_dt,
    const float* __restrict__ D_skip, const float* __restrict__ W_opT,
    const float* __restrict__ b_op,   const float* __restrict__ initial,
    float* __restrict__ xdP, float* __restrict__ pdP,
    int* __restrict__ flags, float* __restrict__ dout)
{
  const int tid  = threadIdx.x;
  const int g    = blockIdx.x & 127;  // group: 4 batch rows
  const int s    = blockIdx.x >> 7;   // slice: 1024 cols; pair block = g+(1-s)*128
  const int r0   = g*4;
  const int lane = tid & 63;
  const int kq   = tid >> 6;          // 0..7
  const int cl   = tid*2;             // local col pair (0..1022)
  const int c0   = s*1024 + cl;       // global x col
  const int cz0  = 2048 + c0;

  __shared__ float predL[256];     // [o*4+r] (pred WITHOUT b_op)
  __shared__ float xyL[4][1024];   // x tile, then y tile [r][local col]
  __shared__ float xdF[768];       // xdbc [n*4+r]
  __shared__ float pdF[256];       // pred partial [o*4+r]
  __shared__ float bcL[4];

  // step-invariant register preloads
  const float cwa = conv_w[c0*4+3];
  const float cwb = conv_w[(c0+1)*4+3];
  const float2 cb  = *(const float2*)&conv_b[c0];
  const float2 cvx = *(const float2*)&cvec[c0];
  const float2 cvz = *(const float2*)&cvec[cz0];
  const float2 bdt = *(const float2*)&b_dt[c0];
  const float2 dsk = *(const float2*)&D_skip[c0];
  const float  bop = b_op[lane];
  float ctxx[8], ctxz[8];
#pragma unroll
  for (int r=0;r<4;r++){
    float2 a = *(const float2*)&ctx_xz[(size_t)(r0+r)*4096 + c0];
    float2 b = *(const float2*)&ctx_xz[(size_t)(r0+r)*4096 + cz0];
    ctxx[r] = a.x; ctxx[4+r] = a.y;
    ctxz[r] = b.x; ctxz[4+r] = b.y;
  }
  ull*       myXd = (ull*)(xdP + ((size_t)s*128 + g)*768);
  const ull* prXd = (const ull*)(xdP + ((size_t)(1-s)*128 + g)*768);
  ull*       myPd = (ull*)(pdP + ((size_t)s*128 + g)*256);
  const ull* prPd = (const ull*)(pdP + ((size_t)(1-s)*128 + g)*256);
  int* flag = flags + g*32;

  if (tid < 256) predL[tid] = initial[(size_t)(r0 + (tid&3))*64 + (tid>>2)];
  __syncthreads();

  float xv[8], zs[8];

  for (int t=0; t<96; t++){
    // ---- phase A: dout(t-1), zero LDS reduction targets, GEMM1 ----
    if (t > 0 && tid < 128){
      int r = s*2 + (tid>>6);
      dout[((size_t)(r0+r)*96 + (t-1))*64 + lane] = predL[lane*4 + r] + bop;
    }
    if (tid >= 192 && tid < 384){
      int i = tid - 192;
      *(float4*)&xdF[i*4] = make_float4(0.f,0.f,0.f,0.f);
    } else if (tid >= 384 && tid < 448){
      int i = tid - 384;
      *(float4*)&pdF[i*4] = make_float4(0.f,0.f,0.f,0.f);
    }

    const float tf = (t > 0) ? 1.f : 0.f;
    float acc[8], zac[8];
#pragma unroll
    for (int r=0;r<4;r++){
      acc[r]   = ctxx[r]   + tf*cvx.x;
      acc[4+r] = ctxx[4+r] + tf*cvx.y;
      zac[r]   = ctxz[r]   + tf*cvz.x;
      zac[4+r] = ctxz[4+r] + tf*cvz.y;
    }
    const float* w2x = w_in2 + c0;
    const float* w2z = w_in2 + cz0;
#pragma unroll 16
    for (int o=0;o<64;o++){
      float4 p  = *(const float4*)&predL[o*4];
      float2 wx = *(const float2*)&w2x[(size_t)o*4096];
      float2 wz = *(const float2*)&w2z[(size_t)o*4096];
      acc[0]+=p.x*wx.x; acc[1]+=p.y*wx.x; acc[2]+=p.z*wx.x; acc[3]+=p.w*wx.x;
      acc[4]+=p.x*wx.y; acc[5]+=p.y*wx.y; acc[6]+=p.z*wx.y; acc[7]+=p.w*wx.y;
      zac[0]+=p.x*wz.x; zac[1]+=p.y*wz.x; zac[2]+=p.z*wz.x; zac[3]+=p.w*wz.x;
      zac[4]+=p.x*wz.y; zac[5]+=p.y*wz.y; zac[6]+=p.z*wz.y; zac[7]+=p.w*wz.y;
    }
#pragma unroll
    for (int r=0;r<4;r++){
      float va = acc[r]*cwa + cb.x;
      float vb = acc[4+r]*cwb + cb.y;
      xv[r]   = va*sigf(va);
      xv[4+r] = vb*sigf(vb);
      zs[r]   = zac[r]*sigf(zac[r]);
      zs[4+r] = zac[4+r]*sigf(zac[4+r]);
      *(float2*)&xyL[r][cl] = make_float2(xv[r], xv[4+r]);
    }
    __syncthreads();   // A: x tile visible, xdF/pdF zeroed

    // ---- xdbc partials over this slice (K=128 per thread via kq) ----
    {
      const float* wxa = w_xT + (size_t)lane*2048 + s*1024;
      const float* wxb = wxa + (size_t)64*2048;
      const float* wxc = wxa + (size_t)128*2048;
      const int kb = kq*128;
      float f0[4]={0,0,0,0}, f1[4]={0,0,0,0}, f2[4]={0,0,0,0};
#pragma unroll 8
      for (int k=kb; k<kb+128; k+=4){
        float4 x0 = *(const float4*)&xyL[0][k];
        float4 x1 = *(const float4*)&xyL[1][k];
        float4 x2 = *(const float4*)&xyL[2][k];
        float4 x3 = *(const float4*)&xyL[3][k];
        float4 wa = *(const float4*)&wxa[k];
        float4 wb = *(const float4*)&wxb[k];
        float4 wc = *(const float4*)&wxc[k];
        f0[0]+=wa.x*x0.x+wa.y*x0.y+wa.z*x0.z+wa.w*x0.w;
        f0[1]+=wa.x*x1.x+wa.y*x1.y+wa.z*x1.z+wa.w*x1.w;
        f0[2]+=wa.x*x2.x+wa.y*x2.y+wa.z*x2.z+wa.w*x2.w;
        f0[3]+=wa.x*x3.x+wa.y*x3.y+wa.z*x3.z+wa.w*x3.w;
        f1[0]+=wb.x*x0.x+wb.y*x0.y+wb.z*x0.z+wb.w*x0.w;
        f1[1]+=wb.x*x1.x+wb.y*x1.y+wb.z*x1.z+wb.w*x1.w;
        f1[2]+=wb.x*x2.x+wb.y*x2.y+wb.z*x2.z+wb.w*x2.w;
        f1[3]+=wb.x*x3.x+wb.y*x3.y+wb.z*x3.z+wb.w*x3.w;
        f2[0]+=wc.x*x0.x+wc.y*x0.y+wc.z*x0.z+wc.w*x0.w;
        f2[1]+=wc.x*x1.x+wc.y*x1.y+wc.z*x1.z+wc.w*x1.w;
        f2[2]+=wc.x*x2.x+wc.y*x2.y+wc.z*x2.z+wc.w*x2.w;
        f2[3]+=wc.x*x3.x+wc.y*x3.y+wc.z*x3.z+wc.w*x3.w;
      }
#pragma unroll
      for (int r=0;r<4;r++){
        atomicAdd(&xdF[lane*4 + r],       f0[r]);
        atomicAdd(&xdF[(lane+64)*4 + r],  f1[r]);
        atomicAdd(&xdF[(lane+128)*4 + r], f2[r]);
      }
    }
    __syncthreads();   // B: block-local xdF complete

    // ---- exchange xdbc partials with pair block ----
    if (tid < 384){
      F2 v; v.f[0] = xdF[tid*2]; v.f[1] = xdF[tid*2+1];
      __hip_atomic_store(&myXd[tid], v.u, __ATOMIC_RELAXED, AGENT);
    }
    gbar(flag, 2*(2*t+1));
    if (tid < 384){
      F2 v; v.u = __hip_atomic_load(&prXd[tid], __ATOMIC_RELAXED, AGENT);
      xdF[tid*2]   += v.f[0];
      xdF[tid*2+1] += v.f[1];
    }
    __syncthreads();   // C: xdF final

    // ---- bc dots (waves 0-3) + dt GEMM (all) ----
    if (tid < 256){
      int r = tid>>6;
      float p = xdF[(64+lane)*4 + r] * xdF[(128+lane)*4 + r];
#pragma unroll
      for (int sh=1; sh<64; sh<<=1) p += __shfl_xor(p, sh, 64);
      if (lane == 0) bcL[r] = p;
    }
    float dacc[8] = {0.f,0.f,0.f,0.f,0.f,0.f,0.f,0.f};
    const float* wdp = w_dt + c0;
#pragma unroll 16
    for (int o=0;o<64;o++){
      float4 xo = *(const float4*)&xdF[o*4];
      float2 wd = *(const float2*)&wdp[(size_t)o*2048];
      dacc[0]+=xo.x*wd.x; dacc[1]+=xo.y*wd.x; dacc[2]+=xo.z*wd.x; dacc[3]+=xo.w*wd.x;
      dacc[4]+=xo.x*wd.y; dacc[5]+=xo.y*wd.y; dacc[6]+=xo.z*wd.y; dacc[7]+=xo.w*wd.y;
    }
    __syncthreads();   // D: bcL ready

    // ---- y and write y tile ----
#pragma unroll
    for (int r=0;r<4;r++){
      float va = dacc[r]   + bdt.x;
      float vb = dacc[4+r] + bdt.y;
      float dta = (va > 15.f) ? va : __logf(1.f + __expf(va));
      float dtb = (vb > 15.f) ? vb : __logf(1.f + __expf(vb));
      float ya = (dta*bcL[r] + dsk.x) * xv[r]   * zs[r];
      float yb = (dtb*bcL[r] + dsk.y) * xv[4+r] * zs[4+r];
      *(float2*)&xyL[r][cl] = make_float2(ya, yb);
    }
    __syncthreads();   // E: y tile visible

    // ---- pred partials over this slice ----
    {
      const float* wop = W_opT + (size_t)lane*2048 + s*1024;
      const int kb = kq*128;
      float pa0=0.f, pa1=0.f, pa2=0.f, pa3=0.f;
#pragma unroll 8
      for (int k=kb; k<kb+128; k+=4){
        float4 w  = *(const float4*)&wop[k];
        float4 y0 = *(const float4*)&xyL[0][k];
        float4 y1 = *(const float4*)&xyL[1][k];
        float4 y2 = *(const float4*)&xyL[2][k];
        float4 y3 = *(const float4*)&xyL[3][k];
        pa0 += w.x*y0.x+w.y*y0.y+w.z*y0.z+w.w*y0.w;
        pa1 += w.x*y1.x+w.y*y1.y+w.z*y1.z+w.w*y1.w;
        pa2 += w.x*y2.x+w.y*y2.y+w.z*y2.z+w.w*y2.w;
        pa3 += w.x*y3.x+w.y*y3.y+w.z*y3.z+w.w*y3.w;
      }
      atomicAdd(&pdF[lane*4+0], pa0);
      atomicAdd(&pdF[lane*4+1], pa1);
      atomicAdd(&pdF[lane*4+2], pa2);
      atomicAdd(&pdF[lane*4+3], pa3);
    }
    __syncthreads();   // F: block-local pred partial complete

    // ---- exchange pred partials, assemble predL ----
    if (tid < 128){
      F2 v; v.f[0] = pdF[tid*2]; v.f[1] = pdF[tid*2+1];
      __hip_atomic_store(&myPd[tid], v.u, __ATOMIC_RELAXED, AGENT);
    }
    gbar(flag, 2*(2*t+2));
    if (tid < 128){
      F2 v; v.u = __hip_atomic_load(&prPd[tid], __ATOMIC_RELAXED, AGENT);
      predL[tid*2]   = pdF[tid*2]   + v.f[0];
      predL[tid*2+1] = pdF[tid*2+1] + v.f[1];
    }
    __syncthreads();   // G: predL valid for next step
  }

  // final pred -> dout (t = 96)
  if (tid < 128){
    int r = s*2 + (tid>>6);
    dout[((size_t)(r0+r)*96 + 95)*64 + lane] = predL[lane*4 + r] + bop;
  }
}

// ---------------- launch ----------------

extern "C" void kernel_launch(void* const* d_in, const int* in_sizes, int n_in,
                              void* d_out, int out_size, void* d_ws, size_t ws_size,
                              hipStream_t stream)
{
  const float* context = (const float*)d_in[0];
  const float* initial = (const float*)d_in[1];
  const float* w_in    = (const float*)d_in[2];
  const float* b_in    = (const float*)d_in[3];
  const float* conv_w  = (const float*)d_in[4];
  const float* conv_b  = (const float*)d_in[5];
  const float* w_x     = (const float*)d_in[6];
  const float* w_dt    = (const float*)d_in[7];
  const float* b_dt    = (const float*)d_in[8];
  // d_in[9] = A_log (unused: L=1, h0=0)
  const float* D_skip  = (const float*)d_in[10];
  const float* w_out   = (const float*)d_in[11];
  const float* b_out   = (const float*)d_in[12];
  const float* w_proj  = (const float*)d_in[13];
  const float* b_proj  = (const float*)d_in[14];

  float* ws = (float*)d_ws;
  float* ctx_xz = ws;                    // 2,097,152
  float* cvec   = ctx_xz + 2097152;      // 4,096
  float* W_opT  = cvec + 4096;           // 131,072
  float* b_op   = W_opT + 131072;        // 128
  float* w_xT   = b_op + 128;            // 393,216
  float* xdP    = w_xT + 393216;         // 196,608 (2 x 128 x 768)
  float* pdP    = xdP + 196608;          // 65,536  (2 x 128 x 256)
  int*   flags  = (int*)(pdP + 65536);   // 4,096 ints
  float* dout   = (float*)d_out;

  const float* w_in2 = w_in + (size_t)1024*4096;

  k_wop <<<dim3(513),   256, 0, stream>>>(w_out, w_proj, b_out, b_proj, W_opT, b_op);
  k_cvec<<<dim3(16),    256, 0, stream>>>(b_op, w_in2, cvec);
  k_ctx <<<dim3(16,32), 256, 0, stream>>>(context, w_in, b_in, ctx_xz);
  k_wxT <<<dim3(8),     256, 0, stream>>>(w_x, w_xT);
  k_zero<<<dim3(16),    256, 0, stream>>>(flags, 4096);

  k_steps<<<dim3(256), 512, 0, stream>>>(ctx_xz, cvec, w_in2, conv_w, conv_b,
                                         w_xT, w_dt, b_dt, D_skip, W_opT, b_op,
                                         initial, xdP, pdP, flags, dout);
}